// Round 20
// baseline (84.480 us; speedup 1.0000x reference)
//
#include <hip/hip_runtime.h>
#include <math.h>

#define NB 8
#define NH 120
#define NW 160
#define HW (NH*NW)
#define NSEM 16
#define NCH 20
#define VR 100
#define NZ 80
#define NZP 40  // z stored as 40 u32 pairs of u16 fields (ch0)
#define ZLO 9
#define ZHI 35
#define NZS (ZHI-ZLO)
#define MD 240
#define PC 20   // proj channel stride (channel-innermost, slot == output channel, 2/3 unused)
#define YW 64   // y-window rows actually touchable by the splat (posy = d/5 in [10,70])
#define YOFF 8
#define QS0    256.0f
#define QS0INV 0.00390625f
#define QS2    8.0f       // sem scale: 4 x u8 fields in one u32 (sum bound ~30 < 31.9)
#define QS2INV 0.125f
#define PXB 120 // pixels per rottrans block (2 blocks per output row)
#define ACCS 124 // s_acc row stride (floats): 16B-aligned, dodges banks
#define GPTS 242 // rotval grid points per block: 2 rows x 121 u-positions

__device__ __forceinline__ float clamp01(float v){ return fminf(fmaxf(v, 0.0f), 1.0f); }

// Scalar-field coordinate/weight computation (exact replica of reference f32 math).
// NO arrays (rule: runtime-indexed arrays -> LDS-promoted allocas, rounds 5/6).
struct SplatCoord {
    float wx0, wx1, wy0, wy1, wz0, wz1;
    int   xi0, xi1, yi0, yi1, zi0, zi1;
};
__device__ __forceinline__ void compute_coord(float d, int h, int w, float fl, SplatCoord& sc) {
    float X = ((float)w - 79.5f) * d / fl;
    float Z = ((float)(119 - h) - 59.5f) * d / fl;
    float pcx = X + 250.0f;
    float pcy = d;
    float pcz = Z + 88.0f;
    float posx = ((pcx/5.0f - 50.0f)/100.0f*2.0f)*50.0f + 50.0f;
    float posy = ((pcy/5.0f - 50.0f)/100.0f*2.0f)*50.0f + 50.0f;
    float posz = ((pcz/5.0f - 32.0f)/80.0f*2.0f)*40.0f + 40.0f;
    float f;
    f = floorf(posx);
    { float pi = f;        bool s = (pi > 0.0f) && (pi < 100.0f);
      sc.wx0 = s ? (1.0f - fabsf(posx - pi)) : 0.0f; sc.xi0 = s ? (int)pi : 0; }
    { float pi = f + 1.0f; bool s = (pi > 0.0f) && (pi < 100.0f);
      sc.wx1 = s ? (1.0f - fabsf(posx - pi)) : 0.0f; sc.xi1 = s ? (int)pi : 0; }
    f = floorf(posy);
    { float pi = f;        bool s = (pi > 0.0f) && (pi < 100.0f);
      sc.wy0 = s ? (1.0f - fabsf(posy - pi)) : 0.0f; sc.yi0 = s ? (int)pi : 0; }
    { float pi = f + 1.0f; bool s = (pi > 0.0f) && (pi < 100.0f);
      sc.wy1 = s ? (1.0f - fabsf(posy - pi)) : 0.0f; sc.yi1 = s ? (int)pi : 0; }
    f = floorf(posz);
    { float pi = f;        bool s = (pi > 0.0f) && (pi < 80.0f);
      sc.wz0 = s ? (1.0f - fabsf(posz - pi)) : 0.0f; sc.zi0 = s ? (int)pi : 0; }
    { float pi = f + 1.0f; bool s = (pi > 0.0f) && (pi < 80.0f);
      sc.wz1 = s ? (1.0f - fabsf(posz - pi)) : 0.0f; sc.zi1 = s ? (int)pi : 0; }
}

// ---------------- batch->XCD pinned zero fill ----------------
__global__ void zero_k(uint4* __restrict__ vox0q4, uint4* __restrict__ voxS4) {
    int b = blockIdx.x & 7;
    int i = ((blockIdx.x >> 3) << 8) + threadIdx.x;   // [0, 230400)
    const uint4 z = make_uint4(0u, 0u, 0u, 0u);
    if (i < 64000) {
        vox0q4[(size_t)b*64000 + i] = z;              // 256,000 u32 per batch
    } else {
        voxS4[(size_t)b*166400 + (i - 64000)] = z;    // 665,600 u32 per batch
    }
}

// ---------------- pose + affine params ----------------
__global__ void pose_k(const float* __restrict__ pose_obs,
                       const float* __restrict__ poses_last,
                       float* __restrict__ out2, float* __restrict__ out3,
                       float* __restrict__ aux) {
    int b = threadIdx.x;
    if (b >= NB) return;
    const float D2R = 0.017453292519943295f;
    float th = poses_last[b*3+2] * D2R;
    float s = sinf(th), c = cosf(th);
    float ny = poses_last[b*3+1] + pose_obs[b*3+0]*s + pose_obs[b*3+1]*c;
    float nx = poses_last[b*3+0] + pose_obs[b*3+0]*c - pose_obs[b*3+1]*s;
    float nt = poses_last[b*3+2] + pose_obs[b*3+2]*57.29577951308232f;
    nt = fmodf(nt - 180.0f, 360.0f) + 180.0f;
    nt = fmodf(nt + 180.0f, 360.0f) - 180.0f;
    out2[b*3+0] = nx; out2[b*3+1] = ny; out2[b*3+2] = nt;
    out3[b*3+0] = nx; out3[b*3+1] = ny; out3[b*3+2] = nt;
    float stt = 90.0f - nt;
    float rad = stt * D2R;
    float tx = -(nx*100.0f/5.0f - 120.0f)/120.0f;
    float ty = -(ny*100.0f/5.0f - 120.0f)/120.0f;
    float dx = tx * 119.5f;
    float dy = ty * 119.5f;
    float Kf = floorf(dx), Lf = floorf(dy);
    aux[b*12+0] = cosf(rad);
    aux[b*12+1] = sinf(rad);
    aux[b*12+2] = Kf;
    aux[b*12+3] = Lf;
    aux[b*12+4] = dx - Kf;   // fx
    aux[b*12+5] = dy - Lf;   // fy
}

// ---------------- merged splat: thread per (pixel, k), batch->XCD pinned ----------------
// R18 shape (best measured). Splat is at an L2 atomic-service-rate floor:
// R16(2.46M thr)=39.4us, R18=39.7, R19(4.9M thr, same atomics)=40.5,
// R17(1.23M thr, half atomics)=50 -> concurrency-insensitive above ~60% occ.
__global__ void splat_k(const float* __restrict__ obs, unsigned* __restrict__ vox0q,
                        unsigned* __restrict__ voxS, float fl) {
    int b = blockIdx.x & 7;
    int idx = ((blockIdx.x >> 3) << 8) + threadIdx.x;   // [0, HW*4)
    if (idx >= HW*4) return;
    int k = idx & 3; int p = idx >> 2;
    int h = p / NW, w = p % NW;
    const float* ob = obs + (size_t)b*NCH*HW;
    float d = ob[3*HW + p];
    SplatCoord sc;
    compute_coord(d, h, w, fl, sc);

    {
        float wxy = ((k & 1) ? sc.wx1 : sc.wx0) * ((k >> 1) ? sc.wy1 : sc.wy0);
        int   xiv = (k & 1) ? sc.xi1 : sc.xi0;
        unsigned ywi = (unsigned)(((k >> 1) ? sc.yi1 : sc.yi0) - YOFF);
        if (wxy != 0.0f && ywi < YW) {
            unsigned q0 = __float2uint_rn(wxy*sc.wz0*QS0);
            unsigned q1 = __float2uint_rn(wxy*sc.wz1*QS0);
            if (q0 | q1) {
                int z0 = sc.zi0, z1 = sc.zi1;
                size_t rowcol = (size_t)ywi*VR + xiv;
                if (q0 && q1 && !(z0 & 1)) {
                    atomicAdd(&vox0q[((size_t)(b*NZP + (z0 >> 1))*YW*VR) + rowcol], q0 | (q1 << 16));
                } else {
                    if (q0) atomicAdd(&vox0q[((size_t)(b*NZP + (z0 >> 1))*YW*VR) + rowcol],
                                      (z0 & 1) ? (q0 << 16) : q0);
                    if (q1) atomicAdd(&vox0q[((size_t)(b*NZP + (z1 >> 1))*YW*VR) + rowcol],
                                      (z1 & 1) ? (q1 << 16) : q1);
                }
            }
        }
    }

    float f0 = ob[(4 + 4*k + 0)*HW + p];
    float f1 = ob[(4 + 4*k + 1)*HW + p];
    float f2 = ob[(4 + 4*k + 2)*HW + p];
    float f3 = ob[(4 + 4*k + 3)*HW + p];
    #pragma unroll
    for (int cz = 0; cz < 2; cz++) {
        int z = cz ? sc.zi1 : sc.zi0;
        float wzv = cz ? sc.wz1 : sc.wz0;
        if (z < ZLO || z >= ZHI) continue;
        #pragma unroll
        for (int cy = 0; cy < 2; cy++) {
            float wyz = (cy ? sc.wy1 : sc.wy0) * wzv;
            unsigned ywi = (unsigned)((cy ? sc.yi1 : sc.yi0) - YOFF);
            if (ywi >= YW) continue;
            #pragma unroll
            for (int cx = 0; cx < 2; cx++) {
                float w3 = (cx ? sc.wx1 : sc.wx0) * wyz;
                int xiv = cx ? sc.xi1 : sc.xi0;
                if (w3 == 0.0f) continue;
                unsigned q0 = __float2uint_rn(f0*w3*QS2);
                unsigned q1 = __float2uint_rn(f1*w3*QS2);
                unsigned q2 = __float2uint_rn(f2*w3*QS2);
                unsigned q3 = __float2uint_rn(f3*w3*QS2);
                unsigned val = q0 | (q1 << 8) | (q2 << 16) | (q3 << 24);
                if (val) {
                    size_t addr = (((((size_t)b*NZS + (z-ZLO))*YW + ywi)*VR + xiv)<<2) + k;
                    atomicAdd(&voxS[addr], val);
                }
            }
        }
    }
}

// ---------------- fused projections: lane-pair z-split, batch->XCD pinned ----------------
// Round 20: 2x waves at identical load count. Lane L and L+32 of a wave handle
// the SAME pixel, z-halves 0/1; one __shfl_down(.,32) per accumulator combines;
// lanes <32 write. rint'ed values are exact integers -> split order bit-identical.
// Per batch: [0,20480) ch0 region, [20480,40960) sem region (64-aligned).
__global__ void proj_k(const unsigned* __restrict__ vox0q, const unsigned* __restrict__ voxS,
                       float* __restrict__ proj, float* __restrict__ out0) {
    int b = blockIdx.x & 7;
    int t2 = ((blockIdx.x >> 3) << 8) + threadIdx.x;   // [0, 40960)
    int lane = threadIdx.x & 63;
    int half = lane >> 5;
    if (t2 < 20480) {
        int r = ((t2 >> 6) << 5) + (lane & 31);        // pixel
        bool valid = r < VR*VR;
        int yy = valid ? (r / VR) : 0;
        bool inwin = valid && (yy >= YOFF) && (yy < YOFF+YW);
        float s_all = 0.0f, s_slab = 0.0f;
        if (inwin) {
            int rw = (yy - YOFF)*VR + (r % VR);
            const unsigned* col = vox0q + (size_t)b*NZP*(YW*VR) + rw;
            int zp0 = half*20;
            #pragma unroll
            for (int i = 0; i < 20; i++) {
                int zp = zp0 + i;
                unsigned v = col[(size_t)zp*(YW*VR)];
                float v0 = rintf((float)(v & 0xFFFFu)*QS0INV);  // z = 2*zp
                float v1 = rintf((float)(v >> 16)*QS0INV);      // z = 2*zp+1
                s_all += v0 + v1;
                if (zp >= 5 && zp <= 16) s_slab += v0 + v1;     // z 10..33
                else if (zp == 4) s_slab += v1;                 // z 9
                else if (zp == 17) s_slab += v0;                // z 34
            }
        }
        s_all  += __shfl_down(s_all, 32);
        s_slab += __shfl_down(s_slab, 32);
        if (valid && half == 0) {
            float* pb = proj + ((size_t)b*(VR*VR) + r)*PC;
            float fpm = inwin ? clamp01(s_slab) : 0.0f;   // MAP_THR = 1
            float fpe = inwin ? clamp01(s_all)  : 0.0f;   // EXP_THR = 1
            out0[(size_t)b*(VR*VR) + r] = fpm;
            *reinterpret_cast<float2*>(pb) = make_float2(fpm, fpe);
        }
        return;
    }
    int u = t2 - 20480;
    int r = ((u >> 6) << 5) + (lane & 31);             // pixel
    bool valid = r < VR*VR;
    int yy = valid ? (r / VR) : 0;
    bool inwin = valid && (yy >= YOFF) && (yy < YOFF+YW);
    float a00=0.f,a01=0.f,a02=0.f,a03=0.f, a10=0.f,a11=0.f,a12=0.f,a13=0.f;
    float a20=0.f,a21=0.f,a22=0.f,a23=0.f, a30=0.f,a31=0.f,a32=0.f,a33=0.f;
    if (inwin) {
        int rw = (yy - YOFF)*VR + (r % VR);
        int zs0 = half*13;
        #pragma unroll
        for (int i = 0; i < 13; i++) {
            int zs = zs0 + i;
            const uint4 v = *reinterpret_cast<const uint4*>(
                voxS + ((((size_t)b*NZS + zs)*(YW*VR) + rw)<<2));
            a00 += rintf((float)( v.x        & 0xFFu)*QS2INV);
            a01 += rintf((float)((v.x >>  8) & 0xFFu)*QS2INV);
            a02 += rintf((float)((v.x >> 16) & 0xFFu)*QS2INV);
            a03 += rintf((float)( v.x >> 24         )*QS2INV);
            a10 += rintf((float)( v.y        & 0xFFu)*QS2INV);
            a11 += rintf((float)((v.y >>  8) & 0xFFu)*QS2INV);
            a12 += rintf((float)((v.y >> 16) & 0xFFu)*QS2INV);
            a13 += rintf((float)( v.y >> 24         )*QS2INV);
            a20 += rintf((float)( v.z        & 0xFFu)*QS2INV);
            a21 += rintf((float)((v.z >>  8) & 0xFFu)*QS2INV);
            a22 += rintf((float)((v.z >> 16) & 0xFFu)*QS2INV);
            a23 += rintf((float)( v.z >> 24         )*QS2INV);
            a30 += rintf((float)( v.w        & 0xFFu)*QS2INV);
            a31 += rintf((float)((v.w >>  8) & 0xFFu)*QS2INV);
            a32 += rintf((float)((v.w >> 16) & 0xFFu)*QS2INV);
            a33 += rintf((float)( v.w >> 24         )*QS2INV);
        }
    }
    a00 += __shfl_down(a00, 32); a01 += __shfl_down(a01, 32);
    a02 += __shfl_down(a02, 32); a03 += __shfl_down(a03, 32);
    a10 += __shfl_down(a10, 32); a11 += __shfl_down(a11, 32);
    a12 += __shfl_down(a12, 32); a13 += __shfl_down(a13, 32);
    a20 += __shfl_down(a20, 32); a21 += __shfl_down(a21, 32);
    a22 += __shfl_down(a22, 32); a23 += __shfl_down(a23, 32);
    a30 += __shfl_down(a30, 32); a31 += __shfl_down(a31, 32);
    a32 += __shfl_down(a32, 32); a33 += __shfl_down(a33, 32);
    if (valid && half == 0) {
        float* dst = proj + ((size_t)b*(VR*VR) + r)*PC + 4;  // 16B aligned, 16 slots
        if (!inwin) {
            *reinterpret_cast<float4*>(dst)      = make_float4(0.0f, 0.0f, 0.0f, 0.0f);
            *reinterpret_cast<float4*>(dst + 4)  = make_float4(0.0f, 0.0f, 0.0f, 0.0f);
            *reinterpret_cast<float4*>(dst + 8)  = make_float4(0.0f, 0.0f, 0.0f, 0.0f);
            *reinterpret_cast<float4*>(dst + 12) = make_float4(0.0f, 0.0f, 0.0f, 0.0f);
        } else {
            *reinterpret_cast<float4*>(dst) = make_float4(
                clamp01(a00/5.0f), clamp01(a01/5.0f), clamp01(a02/5.0f), clamp01(a03/5.0f));
            *reinterpret_cast<float4*>(dst + 4) = make_float4(
                clamp01(a10/5.0f), clamp01(a11/5.0f), clamp01(a12/5.0f), clamp01(a13/5.0f));
            *reinterpret_cast<float4*>(dst + 8) = make_float4(
                clamp01(a20/5.0f), clamp01(a21/5.0f), clamp01(a22/5.0f), clamp01(a23/5.0f));
            *reinterpret_cast<float4*>(dst + 12) = make_float4(
                clamp01(a30/5.0f), clamp01(a31/5.0f), clamp01(a32/5.0f), clamp01(a33/5.0f));
        }
    }
}

// ---------------- rotate+translate + max: rotval-grid version ----------------
__global__ __launch_bounds__(256) void rottrans_k(const float* __restrict__ proj,
                           const float* __restrict__ aux,
                           const float* __restrict__ maps, float* __restrict__ out1) {
    __shared__ float s_rot[GPTS*20];                 // [g][ch] 19360B
    __shared__ unsigned long long s_mix64[1240];     // 9920B: phase0/A = rtap+glive; B/C = s_acc
    unsigned long long* s_rtap = s_mix64;            // [GPTS][4]
    unsigned* s_glive = (unsigned*)(s_mix64 + GPTS*4); // [GPTS]
    float* s_acc = (float*)s_mix64;                  // [20][ACCS]

    int blk = blockIdx.x;
    int b = blk & 7;
    int rem = blk >> 3;          // 0..479
    int Y = rem % MD;
    int chunk = rem / MD;        // 0 or 1
    int X0 = chunk * PXB;
    int t = threadIdx.x;

    float ct = aux[b*12+0], st = aux[b*12+1];
    int K = (int)aux[b*12+2], L = (int)aux[b*12+3];
    float fx = aux[b*12+4], fy = aux[b*12+5];

    // maps prefetch (phase C consumes): issue before any barrier.
    size_t bbase = (size_t)b*NCH*(MD*MD) + (size_t)Y*MD + X0;
    int it0 = t, it1 = t + 256, it2 = t + 512;       // phase C items (ch, px-quad)
    size_t o0 = bbase + (size_t)(it0/30)*(MD*MD) + (it0%30)*4;
    size_t o1 = bbase + (size_t)(it1/30)*(MD*MD) + (it1%30)*4;
    float4 m0 = *reinterpret_cast<const float4*>(maps + o0);
    float4 m1 = *reinterpret_cast<const float4*>(maps + o1);
    float4 m2 = make_float4(0.f,0.f,0.f,0.f);
    size_t o2 = 0;
    if (it2 < PXB/4*NCH) {
        o2 = bbase + (size_t)(it2/30)*(MD*MD) + (it2%30)*4;
        m2 = *reinterpret_cast<const float4*>(maps + o2);
    }

    // Phase 0: rotval geometry for 2x121 grid points.
    if (t < GPTS) {
        int j = (t >= 121) ? 1 : 0;
        int u = t - j*121;
        int U = X0 + K + u;
        int V = Y + L + j;
        unsigned live = 0;
        const float step = 2.0f/239.0f;
        float x2 = 0.0f, y2 = 0.0f;
        bool inr = (U >= 0) && (U < MD) && (V >= 0) && (V < MD);
        if (inr) {
            float Xg2 = (U == MD-1) ? 1.0f : (-1.0f + (float)U*step);
            float Yg2 = (V == MD-1) ? 1.0f : (-1.0f + (float)V*step);
            float ur = ct*Xg2 - st*Yg2;
            float vr = st*Xg2 + ct*Yg2;
            x2 = (ur + 1.0f)*119.5f;
            y2 = (vr + 1.0f)*119.5f;
        }
        float x20 = floorf(x2), y20 = floorf(y2);
        #pragma unroll
        for (int ii = 0; ii < 4; ii++) {
            float jx = x20 + (float)(ii & 1);
            float jy = y20 + (float)(ii >> 1);
            float w2 = ((ii & 1) ? (x2 - x20) : (x20 + 1.0f - x2)) *
                       ((ii >> 1) ? (y2 - y20) : (y20 + 1.0f - y2));
            bool ivalid = inr && (jy >= 120.0f) && (jy < 220.0f) && (jx >= 70.0f) && (jx < 170.0f);
            float w = ivalid ? w2 : 0.0f;
            int  off = ivalid ? (((int)jy - 120)*VR + ((int)jx - 70)) : 0;
            s_rtap[t*4 + ii] = (unsigned long long)(unsigned)off |
                               ((unsigned long long)__float_as_uint(w) << 32);
            live |= (w != 0.0f) ? 1u : 0u;
        }
        s_glive[t] = live;
    }
    __syncthreads();

    // Phase A: rotvals for all channels. items = (g, ch-quad): 1210, float4 taps.
    const float* pj = proj + (size_t)b*(VR*VR)*PC;
    for (int item = t; item < GPTS*5; item += 256) {
        int g = item / 5, q = item % 5;
        float a0 = 0.0f, a1 = 0.0f, a2 = 0.0f, a3 = 0.0f;
        if (s_glive[g]) {
            #pragma unroll
            for (int s = 0; s < 4; s++) {
                unsigned long long tap = s_rtap[g*4 + s];
                float w = __uint_as_float((unsigned)(tap >> 32));
                const float4 v4 = *reinterpret_cast<const float4*>(
                    pj + (size_t)(unsigned)tap*PC + q*4);
                a0 += w*v4.x; a1 += w*v4.y; a2 += w*v4.z; a3 += w*v4.w;
            }
        }
        *reinterpret_cast<float4*>(s_rot + g*20 + q*4) = make_float4(a0, a1, a2, a3);
    }
    __syncthreads();

    // Phase B: constant-weight combine. items = (px, quad).
    float w00 = (1.0f-fx)*(1.0f-fy), w10 = fx*(1.0f-fy);
    float w01 = (1.0f-fx)*fy,        w11 = fx*fy;
    for (int item = t; item < PXB*5; item += 256) {
        int px = item / 5, q = item % 5;
        const float4 r00 = *reinterpret_cast<const float4*>(s_rot + (px      )*20 + q*4);
        const float4 r10 = *reinterpret_cast<const float4*>(s_rot + (px + 1  )*20 + q*4);
        const float4 r01 = *reinterpret_cast<const float4*>(s_rot + (121 + px    )*20 + q*4);
        const float4 r11 = *reinterpret_cast<const float4*>(s_rot + (121 + px + 1)*20 + q*4);
        float a0 = w00*r00.x + w10*r10.x + w01*r01.x + w11*r11.x;
        float a1 = w00*r00.y + w10*r10.y + w01*r01.y + w11*r11.y;
        float a2 = w00*r00.z + w10*r10.z + w01*r01.z + w11*r11.z;
        float a3 = w00*r00.w + w10*r10.w + w01*r01.w + w11*r11.w;
        s_acc[(4*q+0)*ACCS + px] = a0;
        s_acc[(4*q+1)*ACCS + px] = a1;
        s_acc[(4*q+2)*ACCS + px] = a2;
        s_acc[(4*q+3)*ACCS + px] = a3;
    }
    __syncthreads();

    // Phase C: combine with prefetched maps, float4 streaming store.
    {
        int ch = it0/30, pq = it0%30;
        float4 r;
        if (ch == 2 || ch == 3) {
            r = make_float4(fmaxf(m0.x,0.f), fmaxf(m0.y,0.f), fmaxf(m0.z,0.f), fmaxf(m0.w,0.f));
        } else {
            const float4 a = *reinterpret_cast<const float4*>(s_acc + ch*ACCS + pq*4);
            r = make_float4(fmaxf(m0.x,a.x), fmaxf(m0.y,a.y), fmaxf(m0.z,a.z), fmaxf(m0.w,a.w));
        }
        *reinterpret_cast<float4*>(out1 + o0) = r;
    }
    {
        int ch = it1/30, pq = it1%30;
        float4 r;
        if (ch == 2 || ch == 3) {
            r = make_float4(fmaxf(m1.x,0.f), fmaxf(m1.y,0.f), fmaxf(m1.z,0.f), fmaxf(m1.w,0.f));
        } else {
            const float4 a = *reinterpret_cast<const float4*>(s_acc + ch*ACCS + pq*4);
            r = make_float4(fmaxf(m1.x,a.x), fmaxf(m1.y,a.y), fmaxf(m1.z,a.z), fmaxf(m1.w,a.w));
        }
        *reinterpret_cast<float4*>(out1 + o1) = r;
    }
    if (it2 < PXB/4*NCH) {
        int ch = it2/30, pq = it2%30;
        float4 r;
        if (ch == 2 || ch == 3) {
            r = make_float4(fmaxf(m2.x,0.f), fmaxf(m2.y,0.f), fmaxf(m2.z,0.f), fmaxf(m2.w,0.f));
        } else {
            const float4 a = *reinterpret_cast<const float4*>(s_acc + ch*ACCS + pq*4);
            r = make_float4(fmaxf(m2.x,a.x), fmaxf(m2.y,a.y), fmaxf(m2.z,a.z), fmaxf(m2.w,a.w));
        }
        *reinterpret_cast<float4*>(out1 + o2) = r;
    }
}

extern "C" void kernel_launch(void* const* d_in, const int* in_sizes, int n_in,
                              void* d_out, int out_size, void* d_ws, size_t ws_size,
                              hipStream_t stream) {
    const float* obs        = (const float*)d_in[0];
    const float* pose_obs   = (const float*)d_in[1];
    const float* maps_last  = (const float*)d_in[2];
    const float* poses_last = (const float*)d_in[3];
    float* out  = (float*)d_out;
    float* out0 = out;                        // fp_map_pred: 8*1*100*100
    float* out1 = out + 80000;                // map_pred: 8*20*240*240
    float* out2 = out + 80000 + 9216000;      // poses
    float* out3 = out2 + 24;                  // poses (again)

    unsigned* vox0q = (unsigned*)d_ws;                      // 8*40*64*100 u32   = 2,048,000
    unsigned* voxS  = (unsigned*)d_ws + 2048000;            // 8*26*64*100*4 u32 = 5,324,800
    float*    proj  = (float*)d_ws + 2048000 + 5324800;     // 8*100*100*20 f32  = 1,600,000
    float*    aux   = proj + 1600000;                       // 8*12

    const float FLf = (float)(80.0 / tan(39.5 * M_PI / 180.0));

    zero_k    <<<900*8, 256, 0, stream>>>((uint4*)vox0q, (uint4*)voxS);  // batch->XCD pinned zero
    pose_k    <<<1, 64, 0, stream>>>(pose_obs, poses_last, out2, out3, aux);
    splat_k   <<<300*8, 256, 0, stream>>>(obs, vox0q, voxS, FLf);       // 300 blocks/batch, batch=XCD
    proj_k    <<<160*8, 256, 0, stream>>>(vox0q, voxS, proj, out0);     // 160 blocks/batch, lane-pair z-split
    rottrans_k<<<480*8, 256, 0, stream>>>(proj, aux, maps_last, out1);  // 480 blocks/batch
}

// Round 21
// 80.389 us; speedup vs baseline: 1.0509x; 1.0509x over previous
//
#include <hip/hip_runtime.h>
#include <math.h>

#define NB 8
#define NH 120
#define NW 160
#define HW (NH*NW)
#define NSEM 16
#define NCH 20
#define VR 100
#define NZ 80
#define NZP 40  // z stored as 40 u32 pairs of u16 fields (ch0)
#define ZLO 9
#define ZHI 35
#define NZS (ZHI-ZLO)
#define MD 240
#define PC 20   // proj channel stride (channel-innermost, slot == output channel, 2/3 unused)
#define YW 64   // y-window rows actually touchable by the splat (posy = d/5 in [10,70])
#define YOFF 8
#define QS0    256.0f
#define QS0INV 0.00390625f
#define QS2    8.0f       // sem scale: 4 x u8 fields in one u32 (sum bound ~30 < 31.9)
#define QS2INV 0.125f
#define PXB 120 // pixels per rottrans block (2 blocks per output row)
#define ACCS 124 // s_acc row stride (floats): 16B-aligned, dodges banks
#define GPTS 242 // rotval grid points per block: 2 rows x 121 u-positions

__device__ __forceinline__ float clamp01(float v){ return fminf(fmaxf(v, 0.0f), 1.0f); }

// Scalar-field coordinate/weight computation (exact replica of reference f32 math).
// NO arrays (rule: runtime-indexed arrays -> LDS-promoted allocas, rounds 5/6).
struct SplatCoord {
    float wx0, wx1, wy0, wy1, wz0, wz1;
    int   xi0, xi1, yi0, yi1, zi0, zi1;
};
__device__ __forceinline__ void compute_coord(float d, int h, int w, float fl, SplatCoord& sc) {
    float X = ((float)w - 79.5f) * d / fl;
    float Z = ((float)(119 - h) - 59.5f) * d / fl;
    float pcx = X + 250.0f;
    float pcy = d;
    float pcz = Z + 88.0f;
    float posx = ((pcx/5.0f - 50.0f)/100.0f*2.0f)*50.0f + 50.0f;
    float posy = ((pcy/5.0f - 50.0f)/100.0f*2.0f)*50.0f + 50.0f;
    float posz = ((pcz/5.0f - 32.0f)/80.0f*2.0f)*40.0f + 40.0f;
    float f;
    f = floorf(posx);
    { float pi = f;        bool s = (pi > 0.0f) && (pi < 100.0f);
      sc.wx0 = s ? (1.0f - fabsf(posx - pi)) : 0.0f; sc.xi0 = s ? (int)pi : 0; }
    { float pi = f + 1.0f; bool s = (pi > 0.0f) && (pi < 100.0f);
      sc.wx1 = s ? (1.0f - fabsf(posx - pi)) : 0.0f; sc.xi1 = s ? (int)pi : 0; }
    f = floorf(posy);
    { float pi = f;        bool s = (pi > 0.0f) && (pi < 100.0f);
      sc.wy0 = s ? (1.0f - fabsf(posy - pi)) : 0.0f; sc.yi0 = s ? (int)pi : 0; }
    { float pi = f + 1.0f; bool s = (pi > 0.0f) && (pi < 100.0f);
      sc.wy1 = s ? (1.0f - fabsf(posy - pi)) : 0.0f; sc.yi1 = s ? (int)pi : 0; }
    f = floorf(posz);
    { float pi = f;        bool s = (pi > 0.0f) && (pi < 80.0f);
      sc.wz0 = s ? (1.0f - fabsf(posz - pi)) : 0.0f; sc.zi0 = s ? (int)pi : 0; }
    { float pi = f + 1.0f; bool s = (pi > 0.0f) && (pi < 80.0f);
      sc.wz1 = s ? (1.0f - fabsf(posz - pi)) : 0.0f; sc.zi1 = s ? (int)pi : 0; }
}

// ---------------- batch->XCD pinned zero fill ----------------
__global__ void zero_k(uint4* __restrict__ vox0q4, uint4* __restrict__ voxS4) {
    int b = blockIdx.x & 7;
    int i = ((blockIdx.x >> 3) << 8) + threadIdx.x;   // [0, 230400)
    const uint4 z = make_uint4(0u, 0u, 0u, 0u);
    if (i < 64000) {
        vox0q4[(size_t)b*64000 + i] = z;              // 256,000 u32 per batch
    } else {
        voxS4[(size_t)b*166400 + (i - 64000)] = z;    // 665,600 u32 per batch
    }
}

// ---------------- pose + affine params ----------------
__global__ void pose_k(const float* __restrict__ pose_obs,
                       const float* __restrict__ poses_last,
                       float* __restrict__ out2, float* __restrict__ out3,
                       float* __restrict__ aux) {
    int b = threadIdx.x;
    if (b >= NB) return;
    const float D2R = 0.017453292519943295f;
    float th = poses_last[b*3+2] * D2R;
    float s = sinf(th), c = cosf(th);
    float ny = poses_last[b*3+1] + pose_obs[b*3+0]*s + pose_obs[b*3+1]*c;
    float nx = poses_last[b*3+0] + pose_obs[b*3+0]*c - pose_obs[b*3+1]*s;
    float nt = poses_last[b*3+2] + pose_obs[b*3+2]*57.29577951308232f;
    nt = fmodf(nt - 180.0f, 360.0f) + 180.0f;
    nt = fmodf(nt + 180.0f, 360.0f) - 180.0f;
    out2[b*3+0] = nx; out2[b*3+1] = ny; out2[b*3+2] = nt;
    out3[b*3+0] = nx; out3[b*3+1] = ny; out3[b*3+2] = nt;
    float stt = 90.0f - nt;
    float rad = stt * D2R;
    float tx = -(nx*100.0f/5.0f - 120.0f)/120.0f;
    float ty = -(ny*100.0f/5.0f - 120.0f)/120.0f;
    float dx = tx * 119.5f;
    float dy = ty * 119.5f;
    float Kf = floorf(dx), Lf = floorf(dy);
    aux[b*12+0] = cosf(rad);
    aux[b*12+1] = sinf(rad);
    aux[b*12+2] = Kf;
    aux[b*12+3] = Lf;
    aux[b*12+4] = dx - Kf;   // fx
    aux[b*12+5] = dy - Lf;   // fy
}

// ---------------- merged splat: thread per (pixel, k), batch->XCD pinned ----------------
// R18 shape (best measured). Splat is at an L2 atomic-service-rate floor:
// R16(2.46M thr)=39.4us, R18=39.7, R19(4.9M thr, same atomics)=40.5,
// R17(1.23M thr, half atomics)=50 -> concurrency-insensitive above ~60% occ.
__global__ void splat_k(const float* __restrict__ obs, unsigned* __restrict__ vox0q,
                        unsigned* __restrict__ voxS, float fl) {
    int b = blockIdx.x & 7;
    int idx = ((blockIdx.x >> 3) << 8) + threadIdx.x;   // [0, HW*4)
    if (idx >= HW*4) return;
    int k = idx & 3; int p = idx >> 2;
    int h = p / NW, w = p % NW;
    const float* ob = obs + (size_t)b*NCH*HW;
    float d = ob[3*HW + p];
    SplatCoord sc;
    compute_coord(d, h, w, fl, sc);

    {
        float wxy = ((k & 1) ? sc.wx1 : sc.wx0) * ((k >> 1) ? sc.wy1 : sc.wy0);
        int   xiv = (k & 1) ? sc.xi1 : sc.xi0;
        unsigned ywi = (unsigned)(((k >> 1) ? sc.yi1 : sc.yi0) - YOFF);
        if (wxy != 0.0f && ywi < YW) {
            unsigned q0 = __float2uint_rn(wxy*sc.wz0*QS0);
            unsigned q1 = __float2uint_rn(wxy*sc.wz1*QS0);
            if (q0 | q1) {
                int z0 = sc.zi0, z1 = sc.zi1;
                size_t rowcol = (size_t)ywi*VR + xiv;
                if (q0 && q1 && !(z0 & 1)) {
                    atomicAdd(&vox0q[((size_t)(b*NZP + (z0 >> 1))*YW*VR) + rowcol], q0 | (q1 << 16));
                } else {
                    if (q0) atomicAdd(&vox0q[((size_t)(b*NZP + (z0 >> 1))*YW*VR) + rowcol],
                                      (z0 & 1) ? (q0 << 16) : q0);
                    if (q1) atomicAdd(&vox0q[((size_t)(b*NZP + (z1 >> 1))*YW*VR) + rowcol],
                                      (z1 & 1) ? (q1 << 16) : q1);
                }
            }
        }
    }

    float f0 = ob[(4 + 4*k + 0)*HW + p];
    float f1 = ob[(4 + 4*k + 1)*HW + p];
    float f2 = ob[(4 + 4*k + 2)*HW + p];
    float f3 = ob[(4 + 4*k + 3)*HW + p];
    #pragma unroll
    for (int cz = 0; cz < 2; cz++) {
        int z = cz ? sc.zi1 : sc.zi0;
        float wzv = cz ? sc.wz1 : sc.wz0;
        if (z < ZLO || z >= ZHI) continue;
        #pragma unroll
        for (int cy = 0; cy < 2; cy++) {
            float wyz = (cy ? sc.wy1 : sc.wy0) * wzv;
            unsigned ywi = (unsigned)((cy ? sc.yi1 : sc.yi0) - YOFF);
            if (ywi >= YW) continue;
            #pragma unroll
            for (int cx = 0; cx < 2; cx++) {
                float w3 = (cx ? sc.wx1 : sc.wx0) * wyz;
                int xiv = cx ? sc.xi1 : sc.xi0;
                if (w3 == 0.0f) continue;
                unsigned q0 = __float2uint_rn(f0*w3*QS2);
                unsigned q1 = __float2uint_rn(f1*w3*QS2);
                unsigned q2 = __float2uint_rn(f2*w3*QS2);
                unsigned q3 = __float2uint_rn(f3*w3*QS2);
                unsigned val = q0 | (q1 << 8) | (q2 << 16) | (q3 << 24);
                if (val) {
                    size_t addr = (((((size_t)b*NZS + (z-ZLO))*YW + ywi)*VR + xiv)<<2) + k;
                    atomicAdd(&voxS[addr], val);
                }
            }
        }
    }
}

// ---------------- fused projections, batch->XCD pinned (R18 form) ----------------
// R20's lane-pair z-split regressed: splitting z across lane halves doubled the
// distinct lines touched per wave load instruction. Whole-pixel threads keep
// region loads fully coalesced.
__global__ void proj_k(const unsigned* __restrict__ vox0q, const unsigned* __restrict__ voxS,
                       float* __restrict__ proj, float* __restrict__ out0) {
    int b = blockIdx.x & 7;
    int t2 = ((blockIdx.x >> 3) << 8) + threadIdx.x;   // [0, 20224)
    if (t2 < VR*VR) {
        int r = t2;
        int yy = r / VR;
        float* pb = proj + ((size_t)b*(VR*VR) + r)*PC;
        if (yy < YOFF || yy >= YOFF+YW) {
            out0[(size_t)b*(VR*VR) + r] = 0.0f;
            *reinterpret_cast<float2*>(pb) = make_float2(0.0f, 0.0f);
            return;
        }
        int rw = (yy - YOFF)*VR + (r % VR);
        const unsigned* col = vox0q + (size_t)b*NZP*(YW*VR) + rw;
        float s_all = 0.0f, s_slab = 0.0f;
        #pragma unroll
        for (int zp = 0; zp < NZP; zp++) {
            unsigned v = col[(size_t)zp*(YW*VR)];
            float v0 = rintf((float)(v & 0xFFFFu)*QS0INV);  // z = 2*zp
            float v1 = rintf((float)(v >> 16)*QS0INV);      // z = 2*zp+1
            s_all += v0 + v1;
            if (zp >= 5 && zp <= 16) s_slab += v0 + v1;     // z 10..33
            else if (zp == 4) s_slab += v1;                 // z 9
            else if (zp == 17) s_slab += v0;                // z 34
        }
        float fpm = clamp01(s_slab);  // MAP_THR = 1
        float fpe = clamp01(s_all);   // EXP_THR = 1
        out0[(size_t)b*(VR*VR) + r] = fpm;
        *reinterpret_cast<float2*>(pb) = make_float2(fpm, fpe);
        return;
    }
    int r = t2 - VR*VR;
    if (r >= VR*VR) return;
    int yy = r / VR;
    float* dst = proj + ((size_t)b*(VR*VR) + r)*PC + 4;  // 16B aligned, 16 slots
    if (yy < YOFF || yy >= YOFF+YW) {
        *reinterpret_cast<float4*>(dst)      = make_float4(0.0f, 0.0f, 0.0f, 0.0f);
        *reinterpret_cast<float4*>(dst + 4)  = make_float4(0.0f, 0.0f, 0.0f, 0.0f);
        *reinterpret_cast<float4*>(dst + 8)  = make_float4(0.0f, 0.0f, 0.0f, 0.0f);
        *reinterpret_cast<float4*>(dst + 12) = make_float4(0.0f, 0.0f, 0.0f, 0.0f);
        return;
    }
    int rw = (yy - YOFF)*VR + (r % VR);
    float a00=0.f,a01=0.f,a02=0.f,a03=0.f, a10=0.f,a11=0.f,a12=0.f,a13=0.f;
    float a20=0.f,a21=0.f,a22=0.f,a23=0.f, a30=0.f,a31=0.f,a32=0.f,a33=0.f;
    #pragma unroll 13
    for (int zs = 0; zs < NZS; zs++) {
        const uint4 v = *reinterpret_cast<const uint4*>(
            voxS + ((((size_t)b*NZS + zs)*(YW*VR) + rw)<<2));
        a00 += rintf((float)( v.x        & 0xFFu)*QS2INV);
        a01 += rintf((float)((v.x >>  8) & 0xFFu)*QS2INV);
        a02 += rintf((float)((v.x >> 16) & 0xFFu)*QS2INV);
        a03 += rintf((float)( v.x >> 24         )*QS2INV);
        a10 += rintf((float)( v.y        & 0xFFu)*QS2INV);
        a11 += rintf((float)((v.y >>  8) & 0xFFu)*QS2INV);
        a12 += rintf((float)((v.y >> 16) & 0xFFu)*QS2INV);
        a13 += rintf((float)( v.y >> 24         )*QS2INV);
        a20 += rintf((float)( v.z        & 0xFFu)*QS2INV);
        a21 += rintf((float)((v.z >>  8) & 0xFFu)*QS2INV);
        a22 += rintf((float)((v.z >> 16) & 0xFFu)*QS2INV);
        a23 += rintf((float)( v.z >> 24         )*QS2INV);
        a30 += rintf((float)( v.w        & 0xFFu)*QS2INV);
        a31 += rintf((float)((v.w >>  8) & 0xFFu)*QS2INV);
        a32 += rintf((float)((v.w >> 16) & 0xFFu)*QS2INV);
        a33 += rintf((float)( v.w >> 24         )*QS2INV);
    }
    *reinterpret_cast<float4*>(dst) = make_float4(
        clamp01(a00/5.0f), clamp01(a01/5.0f), clamp01(a02/5.0f), clamp01(a03/5.0f));
    *reinterpret_cast<float4*>(dst + 4) = make_float4(
        clamp01(a10/5.0f), clamp01(a11/5.0f), clamp01(a12/5.0f), clamp01(a13/5.0f));
    *reinterpret_cast<float4*>(dst + 8) = make_float4(
        clamp01(a20/5.0f), clamp01(a21/5.0f), clamp01(a22/5.0f), clamp01(a23/5.0f));
    *reinterpret_cast<float4*>(dst + 12) = make_float4(
        clamp01(a30/5.0f), clamp01(a31/5.0f), clamp01(a32/5.0f), clamp01(a33/5.0f));
}

// ---------------- rotate+translate + max: rotval-grid version ----------------
__global__ __launch_bounds__(256) void rottrans_k(const float* __restrict__ proj,
                           const float* __restrict__ aux,
                           const float* __restrict__ maps, float* __restrict__ out1) {
    __shared__ float s_rot[GPTS*20];                 // [g][ch] 19360B
    __shared__ unsigned long long s_mix64[1240];     // 9920B: phase0/A = rtap+glive; B/C = s_acc
    unsigned long long* s_rtap = s_mix64;            // [GPTS][4]
    unsigned* s_glive = (unsigned*)(s_mix64 + GPTS*4); // [GPTS]
    float* s_acc = (float*)s_mix64;                  // [20][ACCS]

    int blk = blockIdx.x;
    int b = blk & 7;
    int rem = blk >> 3;          // 0..479
    int Y = rem % MD;
    int chunk = rem / MD;        // 0 or 1
    int X0 = chunk * PXB;
    int t = threadIdx.x;

    float ct = aux[b*12+0], st = aux[b*12+1];
    int K = (int)aux[b*12+2], L = (int)aux[b*12+3];
    float fx = aux[b*12+4], fy = aux[b*12+5];

    // maps prefetch (phase C consumes): issue before any barrier.
    size_t bbase = (size_t)b*NCH*(MD*MD) + (size_t)Y*MD + X0;
    int it0 = t, it1 = t + 256, it2 = t + 512;       // phase C items (ch, px-quad)
    size_t o0 = bbase + (size_t)(it0/30)*(MD*MD) + (it0%30)*4;
    size_t o1 = bbase + (size_t)(it1/30)*(MD*MD) + (it1%30)*4;
    float4 m0 = *reinterpret_cast<const float4*>(maps + o0);
    float4 m1 = *reinterpret_cast<const float4*>(maps + o1);
    float4 m2 = make_float4(0.f,0.f,0.f,0.f);
    size_t o2 = 0;
    if (it2 < PXB/4*NCH) {
        o2 = bbase + (size_t)(it2/30)*(MD*MD) + (it2%30)*4;
        m2 = *reinterpret_cast<const float4*>(maps + o2);
    }

    // Phase 0: rotval geometry for 2x121 grid points.
    if (t < GPTS) {
        int j = (t >= 121) ? 1 : 0;
        int u = t - j*121;
        int U = X0 + K + u;
        int V = Y + L + j;
        unsigned live = 0;
        const float step = 2.0f/239.0f;
        float x2 = 0.0f, y2 = 0.0f;
        bool inr = (U >= 0) && (U < MD) && (V >= 0) && (V < MD);
        if (inr) {
            float Xg2 = (U == MD-1) ? 1.0f : (-1.0f + (float)U*step);
            float Yg2 = (V == MD-1) ? 1.0f : (-1.0f + (float)V*step);
            float ur = ct*Xg2 - st*Yg2;
            float vr = st*Xg2 + ct*Yg2;
            x2 = (ur + 1.0f)*119.5f;
            y2 = (vr + 1.0f)*119.5f;
        }
        float x20 = floorf(x2), y20 = floorf(y2);
        #pragma unroll
        for (int ii = 0; ii < 4; ii++) {
            float jx = x20 + (float)(ii & 1);
            float jy = y20 + (float)(ii >> 1);
            float w2 = ((ii & 1) ? (x2 - x20) : (x20 + 1.0f - x2)) *
                       ((ii >> 1) ? (y2 - y20) : (y20 + 1.0f - y2));
            bool ivalid = inr && (jy >= 120.0f) && (jy < 220.0f) && (jx >= 70.0f) && (jx < 170.0f);
            float w = ivalid ? w2 : 0.0f;
            int  off = ivalid ? (((int)jy - 120)*VR + ((int)jx - 70)) : 0;
            s_rtap[t*4 + ii] = (unsigned long long)(unsigned)off |
                               ((unsigned long long)__float_as_uint(w) << 32);
            live |= (w != 0.0f) ? 1u : 0u;
        }
        s_glive[t] = live;
    }
    __syncthreads();

    // Phase A: rotvals for all channels. items = (g, ch-quad): 1210, float4 taps.
    const float* pj = proj + (size_t)b*(VR*VR)*PC;
    for (int item = t; item < GPTS*5; item += 256) {
        int g = item / 5, q = item % 5;
        float a0 = 0.0f, a1 = 0.0f, a2 = 0.0f, a3 = 0.0f;
        if (s_glive[g]) {
            #pragma unroll
            for (int s = 0; s < 4; s++) {
                unsigned long long tap = s_rtap[g*4 + s];
                float w = __uint_as_float((unsigned)(tap >> 32));
                const float4 v4 = *reinterpret_cast<const float4*>(
                    pj + (size_t)(unsigned)tap*PC + q*4);
                a0 += w*v4.x; a1 += w*v4.y; a2 += w*v4.z; a3 += w*v4.w;
            }
        }
        *reinterpret_cast<float4*>(s_rot + g*20 + q*4) = make_float4(a0, a1, a2, a3);
    }
    __syncthreads();

    // Phase B: constant-weight combine. items = (px, quad).
    float w00 = (1.0f-fx)*(1.0f-fy), w10 = fx*(1.0f-fy);
    float w01 = (1.0f-fx)*fy,        w11 = fx*fy;
    for (int item = t; item < PXB*5; item += 256) {
        int px = item / 5, q = item % 5;
        const float4 r00 = *reinterpret_cast<const float4*>(s_rot + (px      )*20 + q*4);
        const float4 r10 = *reinterpret_cast<const float4*>(s_rot + (px + 1  )*20 + q*4);
        const float4 r01 = *reinterpret_cast<const float4*>(s_rot + (121 + px    )*20 + q*4);
        const float4 r11 = *reinterpret_cast<const float4*>(s_rot + (121 + px + 1)*20 + q*4);
        float a0 = w00*r00.x + w10*r10.x + w01*r01.x + w11*r11.x;
        float a1 = w00*r00.y + w10*r10.y + w01*r01.y + w11*r11.y;
        float a2 = w00*r00.z + w10*r10.z + w01*r01.z + w11*r11.z;
        float a3 = w00*r00.w + w10*r10.w + w01*r01.w + w11*r11.w;
        s_acc[(4*q+0)*ACCS + px] = a0;
        s_acc[(4*q+1)*ACCS + px] = a1;
        s_acc[(4*q+2)*ACCS + px] = a2;
        s_acc[(4*q+3)*ACCS + px] = a3;
    }
    __syncthreads();

    // Phase C: combine with prefetched maps, float4 streaming store.
    {
        int ch = it0/30, pq = it0%30;
        float4 r;
        if (ch == 2 || ch == 3) {
            r = make_float4(fmaxf(m0.x,0.f), fmaxf(m0.y,0.f), fmaxf(m0.z,0.f), fmaxf(m0.w,0.f));
        } else {
            const float4 a = *reinterpret_cast<const float4*>(s_acc + ch*ACCS + pq*4);
            r = make_float4(fmaxf(m0.x,a.x), fmaxf(m0.y,a.y), fmaxf(m0.z,a.z), fmaxf(m0.w,a.w));
        }
        *reinterpret_cast<float4*>(out1 + o0) = r;
    }
    {
        int ch = it1/30, pq = it1%30;
        float4 r;
        if (ch == 2 || ch == 3) {
            r = make_float4(fmaxf(m1.x,0.f), fmaxf(m1.y,0.f), fmaxf(m1.z,0.f), fmaxf(m1.w,0.f));
        } else {
            const float4 a = *reinterpret_cast<const float4*>(s_acc + ch*ACCS + pq*4);
            r = make_float4(fmaxf(m1.x,a.x), fmaxf(m1.y,a.y), fmaxf(m1.z,a.z), fmaxf(m1.w,a.w));
        }
        *reinterpret_cast<float4*>(out1 + o1) = r;
    }
    if (it2 < PXB/4*NCH) {
        int ch = it2/30, pq = it2%30;
        float4 r;
        if (ch == 2 || ch == 3) {
            r = make_float4(fmaxf(m2.x,0.f), fmaxf(m2.y,0.f), fmaxf(m2.z,0.f), fmaxf(m2.w,0.f));
        } else {
            const float4 a = *reinterpret_cast<const float4*>(s_acc + ch*ACCS + pq*4);
            r = make_float4(fmaxf(m2.x,a.x), fmaxf(m2.y,a.y), fmaxf(m2.z,a.z), fmaxf(m2.w,a.w));
        }
        *reinterpret_cast<float4*>(out1 + o2) = r;
    }
}

extern "C" void kernel_launch(void* const* d_in, const int* in_sizes, int n_in,
                              void* d_out, int out_size, void* d_ws, size_t ws_size,
                              hipStream_t stream) {
    const float* obs        = (const float*)d_in[0];
    const float* pose_obs   = (const float*)d_in[1];
    const float* maps_last  = (const float*)d_in[2];
    const float* poses_last = (const float*)d_in[3];
    float* out  = (float*)d_out;
    float* out0 = out;                        // fp_map_pred: 8*1*100*100
    float* out1 = out + 80000;                // map_pred: 8*20*240*240
    float* out2 = out + 80000 + 9216000;      // poses
    float* out3 = out2 + 24;                  // poses (again)

    unsigned* vox0q = (unsigned*)d_ws;                      // 8*40*64*100 u32   = 2,048,000
    unsigned* voxS  = (unsigned*)d_ws + 2048000;            // 8*26*64*100*4 u32 = 5,324,800
    float*    proj  = (float*)d_ws + 2048000 + 5324800;     // 8*100*100*20 f32  = 1,600,000
    float*    aux   = proj + 1600000;                       // 8*12

    const float FLf = (float)(80.0 / tan(39.5 * M_PI / 180.0));

    zero_k    <<<900*8, 256, 0, stream>>>((uint4*)vox0q, (uint4*)voxS);  // batch->XCD pinned zero
    pose_k    <<<1, 64, 0, stream>>>(pose_obs, poses_last, out2, out3, aux);
    splat_k   <<<300*8, 256, 0, stream>>>(obs, vox0q, voxS, FLf);       // 300 blocks/batch, batch=XCD
    proj_k    <<<79*8, 256, 0, stream>>>(vox0q, voxS, proj, out0);      // 79 blocks/batch
    rottrans_k<<<480*8, 256, 0, stream>>>(proj, aux, maps_last, out1);  // 480 blocks/batch
}